// Round 8
// baseline (836.739 us; speedup 1.0000x reference)
//
#include <hip/hip_runtime.h>

#define N_PTS 131072
#define KC    512
#define DIM   64
#define MAXIT 5
#define NCHUNK 64
#define CHUNK_PTS (N_PTS / NCHUNK)    // 2048
#define FIXSCALE 1099511627776.0      // 2^40
#define XSTR 68                       // LDS row stride (64+4): breaks bank aliasing

// ---------------------------------------------------------------------------
// c2 kernel (iter 0 only): c2[k] = sum_d C[k][d]^2, squares rounded then
// pairwise tree — identical value tree to round 2 (which passed).
// ---------------------------------------------------------------------------
__global__ __launch_bounds__(256) void c2_kernel(const float* __restrict__ C,
                                                 float* __restrict__ c2out) {
    int k = blockIdx.x * 256 + threadIdx.x;
    if (k < KC) {
        float sq[DIM];
        #pragma unroll
        for (int j = 0; j < DIM; ++j) {
            float c = C[k * DIM + j];
            sq[j] = c * c;
        }
        #pragma unroll
        for (int st = 1; st < DIM; st <<= 1)
            #pragma unroll
            for (int j = 0; j < DIM; j += 2 * st)
                sq[j] = sq[j] + sq[j + st];
        c2out[k] = sq[0];
    }
}

// ---------------------------------------------------------------------------
// assign kernel, ROUND 8: register-blocked LDS GEMM.
// Block = 64 points (Xt in LDS, stride 68), loops 8 center-tiles of 64
// (Ct in LDS). Lane grid: cg = lane>>2 (16 center-groups), pg = lane&3
// (4 point-groups). Per lane: 4 points (w*16+pg*4+i) x 4 centers (cg+16j),
// accumulated in float4 a[i][j] — components ARE the round-2 4-acc chain
// (.x sums d=0,4,..,60 in order = a0, etc.), so d2 per (n,k) is bit-identical
// to rounds 2/5/6/7. Center mapping cg+16j makes the 16 distinct C-frag
// ds_read_b128 addresses spread 8 banks x 2-way (free); X-frag reads are
// 16-lane broadcasts. 64 fmas per 8 ds_reads = 8x operand reuse (the round
// 5-7 structure had 1x and stalled at 136 us / 60% VALU).
// Argmin: running u64 keys (monotone map | k), min over tiles/lanes —
// order-independent, ties -> smaller k: exact jnp.argmin semantics.
// ---------------------------------------------------------------------------
__global__ __launch_bounds__(256) void assign_kernel(
        const float* __restrict__ X, const float* __restrict__ C,
        const float* __restrict__ c2v,
        int* __restrict__ asn, float* __restrict__ out_f) {
    __shared__ float Xt[64 * XSTR];
    __shared__ float Ct[64 * XSTR];
    __shared__ float c2t[64];
    __shared__ float x2p[64 * 4];
    __shared__ float x2f[64];

    const int t  = threadIdx.x;
    const int pt = t >> 2;        // 0..63: row this thread stages
    const int q  = t & 3;         // quarter (16 floats) within the row

    // ---- stage X tile + per-quarter x2 subtree (tree level 4, exact order)
    {
        const float* xg = X + ((size_t)blockIdx.x * 64 + pt) * DIM + q * 16;
        float4 v0 = *(const float4*)(xg + 0);
        float4 v1 = *(const float4*)(xg + 4);
        float4 v2 = *(const float4*)(xg + 8);
        float4 v3 = *(const float4*)(xg + 12);
        float* xw = &Xt[pt * XSTR + q * 16];
        *(float4*)(xw + 0)  = v0;
        *(float4*)(xw + 4)  = v1;
        *(float4*)(xw + 8)  = v2;
        *(float4*)(xw + 12) = v3;
        float s[16] = { v0.x*v0.x, v0.y*v0.y, v0.z*v0.z, v0.w*v0.w,
                        v1.x*v1.x, v1.y*v1.y, v1.z*v1.z, v1.w*v1.w,
                        v2.x*v2.x, v2.y*v2.y, v2.z*v2.z, v2.w*v2.w,
                        v3.x*v3.x, v3.y*v3.y, v3.z*v3.z, v3.w*v3.w };
        #pragma unroll
        for (int st = 1; st < 16; st <<= 1)
            #pragma unroll
            for (int j2 = 0; j2 < 16; j2 += 2 * st)
                s[j2] = s[j2] + s[j2 + st];
        x2p[pt * 4 + q] = s[0];
    }

    const int w  = t >> 6;        // wave: handles points w*16 .. w*16+15
    const int l  = t & 63;
    const int cg = l >> 2;        // 0..15 center-group
    const int pg = l & 3;         // 0..3 point-group
    const float* xb = &Xt[(w * 16 + pg * 4) * XSTR];
    const float* cb = &Ct[cg * XSTR];

    unsigned long long bk[4] = { ~0ull, ~0ull, ~0ull, ~0ull };

    for (int kt = 0; kt < 8; ++kt) {
        __syncthreads();   // kt=0: Xt/x2p ready; kt>0: prev GEMM done with Ct
        {
            const float* cgp = C + ((size_t)(kt * 64 + pt)) * DIM + q * 16;
            float4 u0 = *(const float4*)(cgp + 0);
            float4 u1 = *(const float4*)(cgp + 4);
            float4 u2 = *(const float4*)(cgp + 8);
            float4 u3 = *(const float4*)(cgp + 12);
            float* cw = &Ct[pt * XSTR + q * 16];
            *(float4*)(cw + 0)  = u0;
            *(float4*)(cw + 4)  = u1;
            *(float4*)(cw + 8)  = u2;
            *(float4*)(cw + 12) = u3;
            if (t < 64) {
                c2t[t] = c2v[kt * 64 + t];
                if (kt == 0)
                    x2f[t] = (x2p[t * 4 + 0] + x2p[t * 4 + 1])
                           + (x2p[t * 4 + 2] + x2p[t * 4 + 3]);
            }
        }
        __syncthreads();

        float4 a[4][4];
        #pragma unroll
        for (int i = 0; i < 4; ++i)
            #pragma unroll
            for (int j = 0; j < 4; ++j)
                a[i][j] = make_float4(0.f, 0.f, 0.f, 0.f);

        #pragma unroll 4
        for (int c = 0; c < 16; ++c) {
            float4 xf[4], cf[4];
            #pragma unroll
            for (int i = 0; i < 4; ++i)
                xf[i] = *(const float4*)&xb[i * XSTR + c * 4];
            #pragma unroll
            for (int j = 0; j < 4; ++j)
                cf[j] = *(const float4*)&cb[j * (16 * XSTR) + c * 4];
            #pragma unroll
            for (int i = 0; i < 4; ++i)
                #pragma unroll
                for (int j = 0; j < 4; ++j) {
                    a[i][j].x = fmaf(xf[i].x, cf[j].x, a[i][j].x);
                    a[i][j].y = fmaf(xf[i].y, cf[j].y, a[i][j].y);
                    a[i][j].z = fmaf(xf[i].z, cf[j].z, a[i][j].z);
                    a[i][j].w = fmaf(xf[i].w, cf[j].w, a[i][j].w);
                }
        }

        float xx[4];
        #pragma unroll
        for (int i = 0; i < 4; ++i) xx[i] = x2f[w * 16 + pg * 4 + i];

        #pragma unroll
        for (int j = 0; j < 4; ++j) {
            float cc = c2t[cg + 16 * j];
            unsigned int kk = (unsigned int)(kt * 64 + cg + 16 * j);
            #pragma unroll
            for (int i = 0; i < 4; ++i) {
                float dot = (a[i][j].x + a[i][j].y) + (a[i][j].z + a[i][j].w);
                float tt  = xx[i] + cc;          // rounded at d2 scale, matches np
                float d2  = tt - 2.0f * dot;     // 2*dot exact
                unsigned int b = __float_as_uint(d2);
                b = (b & 0x80000000u) ? ~b : (b | 0x80000000u);
                unsigned long long key = ((unsigned long long)b << 32) | kk;
                if (key < bk[i]) bk[i] = key;
            }
        }
    }

    // min over the 16 center-groups (lane bits 2..5 -> xor strides 4..32)
    #pragma unroll
    for (int i = 0; i < 4; ++i) {
        #pragma unroll
        for (int st = 4; st <= 32; st <<= 1) {
            unsigned long long o = __shfl_xor(bk[i], st, 64);
            if (o < bk[i]) bk[i] = o;
        }
    }
    if (cg == 0) {
        #pragma unroll
        for (int i = 0; i < 4; ++i) {
            int p = blockIdx.x * 64 + w * 16 + pg * 4 + i;
            int k = (int)(unsigned int)bk[i];
            asn[p] = k;
            out_f[p] = (float)k;
        }
    }
}

// ---------------------------------------------------------------------------
// accumulate: 256 blocks = 64 chunks (2048 pts) x 4 dim-slices (16 dims).
// INT64 FIXED-POINT (scale 2^40) LDS + global atomics: integer addition is
// exactly order-independent -> bit-deterministic across graph replays.
// ---------------------------------------------------------------------------
__global__ __launch_bounds__(256) void accum_kernel(
        const float* __restrict__ X, const int* __restrict__ asn,
        unsigned long long* __restrict__ qsums, int* __restrict__ counts) {
    __shared__ unsigned long long lsum[KC * 16];   // 64 KB
    __shared__ int lcnt[KC];
    int slice = blockIdx.x & 3;
    int chunk = blockIdx.x >> 2;
    int p4 = threadIdx.x >> 2;   // 0..63: point lane
    int c4 = threadIdx.x & 3;    // float4 slot within the 16-dim slice

    for (int i = threadIdx.x; i < KC * 16; i += 256) lsum[i] = 0ull;
    for (int i = threadIdx.x; i < KC; i += 256) lcnt[i] = 0;
    __syncthreads();

    int base = chunk * CHUNK_PTS;
    #pragma unroll 2
    for (int it = 0; it < CHUNK_PTS / 64; ++it) {
        int n = base + it * 64 + p4;
        int a = asn[n];
        float4 xv = *(const float4*)(X + (size_t)n * DIM + slice * 16 + c4 * 4);
        long long q0 = (long long)llrint((double)xv.x * FIXSCALE);
        long long q1 = (long long)llrint((double)xv.y * FIXSCALE);
        long long q2 = (long long)llrint((double)xv.z * FIXSCALE);
        long long q3 = (long long)llrint((double)xv.w * FIXSCALE);
        atomicAdd(&lsum[a * 16 + c4 * 4 + 0], (unsigned long long)q0);
        atomicAdd(&lsum[a * 16 + c4 * 4 + 1], (unsigned long long)q1);
        atomicAdd(&lsum[a * 16 + c4 * 4 + 2], (unsigned long long)q2);
        atomicAdd(&lsum[a * 16 + c4 * 4 + 3], (unsigned long long)q3);
        if (slice == 0 && c4 == 0) atomicAdd(&lcnt[a], 1);
    }
    __syncthreads();

    for (int i = threadIdx.x; i < KC * 16; i += 256) {
        unsigned long long v = lsum[i];
        if (v != 0ull) {
            int k  = i >> 4;
            int dd = i & 15;
            atomicAdd(&qsums[k * DIM + slice * 16 + dd], v);
        }
    }
    if (slice == 0)
        for (int i = threadIdx.x; i < KC; i += 256) {
            int v = lcnt[i];
            if (v != 0) atomicAdd(&counts[i], v);
        }
}

// ---------------------------------------------------------------------------
// update: new_centers = sums / max(counts,1); element-wise ==0 entries
// re-seeded from X[repl_idx[i]]. Fuses next iteration's c2 via butterfly
// shuffle (identical summation tree to c2_kernel). One wave per cluster.
// ---------------------------------------------------------------------------
__global__ __launch_bounds__(256) void update_kernel(
        const unsigned long long* __restrict__ qsums,
        const int* __restrict__ counts,
        const int* __restrict__ repl, const float* __restrict__ X,
        float* __restrict__ Cws, float* __restrict__ outC,
        float* __restrict__ c2v) {
    int k = blockIdx.x * 4 + (threadIdx.x >> 6);
    int d = threadIdx.x & 63;

    long long q = (long long)qsums[k * DIM + d];
    float s = (float)((double)q * (1.0 / FIXSCALE));
    float cnt = (float)counts[k];
    float v = s / fmaxf(cnt, 1.0f);
    if (v == 0.0f) v = X[(size_t)repl[k] * DIM + d];
    Cws[k * DIM + d]  = v;
    outC[k * DIM + d] = v;

    float sq = v * v;
    #pragma unroll
    for (int st = 1; st < 64; st <<= 1)
        sq += __shfl_xor(sq, st, 64);
    if (d == 0) c2v[k] = sq;
}

// ---------------------------------------------------------------------------
extern "C" void kernel_launch(void* const* d_in, const int* in_sizes, int n_in,
                              void* d_out, int out_size, void* d_ws, size_t ws_size,
                              hipStream_t stream) {
    const float* X    = (const float*)d_in[0];   // [N, D]
    const float* C0   = (const float*)d_in[1];   // [K, D]
    const int*   repl = (const int*)d_in[2];     // [MAXIT, K]
    float* out = (float*)d_out;                  // [N] assignments + [K*D] centers

    // Total ws footprint: 900 KB (round 2's 920 KB proved safe; round 3's
    // 12.8 MB failed with poison-pattern errors -> keep it small).
    char* ws = (char*)d_ws;
    int*   asn    = (int*)  (ws + 0);                        // 512 KB
    float* Cws    = (float*)(ws + (512 << 10));              // 128 KB
    unsigned long long* qsums = (unsigned long long*)(ws + (640 << 10)); // 256 KB
    int*   counts = (int*)  (ws + (896 << 10));              // 2 KB (contiguous w/ qsums)
    float* c2v    = (float*)(ws + (898 << 10));              // 2 KB

    c2_kernel<<<2, 256, 0, stream>>>(C0, c2v);

    for (int i = 0; i < MAXIT; ++i) {
        const float* C = (i == 0) ? C0 : Cws;

        assign_kernel<<<N_PTS / 64, 256, 0, stream>>>(X, C, c2v, asn, out);

        // zero qsums (256 KB) + counts (2 KB), contiguous
        hipMemsetAsync(qsums, 0, KC * DIM * sizeof(unsigned long long)
                                 + KC * sizeof(int), stream);

        accum_kernel<<<NCHUNK * 4, 256, 0, stream>>>(X, asn, qsums, counts);

        update_kernel<<<KC / 4, 256, 0, stream>>>(
            qsums, counts, repl + i * KC, X, Cws, out + N_PTS, c2v);
    }
}